// Round 8
// baseline (405.986 us; speedup 1.0000x reference)
//
#include <hip/hip_runtime.h>
#include <hip/hip_bf16.h>

typedef __bf16 bf16;
typedef __attribute__((ext_vector_type(8))) __bf16 bf16x8;
typedef __attribute__((ext_vector_type(4))) __bf16 bf16x4;
typedef __attribute__((ext_vector_type(4))) float f32x4;

#define MFMA16(a, b, c) __builtin_amdgcn_mfma_f32_16x16x32_bf16((a), (b), (c), 0, 0, 0)
#define SM_SCALE 0.18033688011112043f  // (1/8) * log2(e), folded into q at GEMM epilogue

__device__ __forceinline__ void gld_lds16(const bf16* g, bf16* l) {
    __builtin_amdgcn_global_load_lds((const __attribute__((address_space(1))) void*)g,
                                     (__attribute__((address_space(3))) void*)l, 16, 0, 0);
}

// ---------------- f32 -> bf16 convert (x) ----------------
__global__ __launch_bounds__(256) void cvt_x(const float* __restrict__ in,
                                             bf16* __restrict__ outb, int n) {
    int i = (blockIdx.x * 256 + threadIdx.x) * 4;
    if (i + 3 < n) {
        const float4 v = *(const float4*)(in + i);
        bf16x4 o = {(bf16)v.x, (bf16)v.y, (bf16)v.z, (bf16)v.w};
        *(bf16x4*)(outb + i) = o;
    }
}

// ---------------- W [K][N] f32 -> Wt [N][K] bf16, 3 weights in one launch ----------------
__global__ __launch_bounds__(256) void transpose_w3(const float* __restrict__ W0,
                                                    const float* __restrict__ W1,
                                                    const float* __restrict__ W2,
                                                    bf16* __restrict__ Wt) {
    const float* W = (blockIdx.z == 0) ? W0 : ((blockIdx.z == 1) ? W1 : W2);
    bf16* dst = Wt + (size_t)blockIdx.z * 1024 * 1024;
    __shared__ float tile[64][65];
    const int r0 = blockIdx.y * 64;  // k
    const int c0 = blockIdx.x * 64;  // n
    const int tid = threadIdx.x;
    for (int i = tid; i < 4096; i += 256) {
        int r = i >> 6, cc = i & 63;
        tile[r][cc] = W[(size_t)(r0 + r) * 1024 + c0 + cc];
    }
    __syncthreads();
    for (int i = tid; i < 4096; i += 256) {
        int n = i >> 6, k = i & 63;
        dst[(size_t)(c0 + n) * 1024 + r0 + k] = (bf16)tile[k][n];
    }
}

// ---------------- GEMM: C = A[M,K] @ Bt[N,K]^T + bias ----------------
// MODE 0: fused QKV (N=3072): q output pre-scaled by SM_SCALE; v written
//         transposed into Vt[bh][d][t].   MODE 1: f32 output, N=1024.
template <int MODE>
__global__ __launch_bounds__(256) void gemm_bt(const bf16* __restrict__ A,
                                               const bf16* __restrict__ Bt,
                                               const float* __restrict__ b0,
                                               const float* __restrict__ b1,
                                               const float* __restrict__ b2,
                                               void* __restrict__ out0,
                                               void* __restrict__ out1,
                                               void* __restrict__ out2,
                                               int M, int N, int K) {
    __shared__ alignas(16) bf16 As[128 * 32];
    __shared__ alignas(16) bf16 Bs[128 * 32];
    const int tid = threadIdx.x;
    const int wave = tid >> 6, lane = tid & 63;
    const int quad = lane >> 4, l16 = lane & 15;
    const int m0 = blockIdx.y * 128, n0 = blockIdx.x * 128;
    const int wm = (wave & 1) * 64, wn = (wave >> 1) * 64;

    f32x4 acc[4][4] = {};

    const int srow = lane >> 2, scol = (lane & 3) * 8;
    const bf16* ga = A + (size_t)(m0 + wave * 32 + srow) * K + scol;
    const bf16* gb = Bt + (size_t)(n0 + wave * 32 + srow) * K + scol;
    bf16* la = &As[(wave * 32) * 32];
    bf16* lb = &Bs[(wave * 32) * 32];

    for (int k0 = 0; k0 < K; k0 += 32) {
        __syncthreads();
        gld_lds16(ga + k0, la);
        gld_lds16(ga + k0 + (size_t)16 * K, la + 16 * 32);
        gld_lds16(gb + k0, lb);
        gld_lds16(gb + k0 + (size_t)16 * K, lb + 16 * 32);
        __syncthreads();
        bf16x8 af[4], bfr[4];
#pragma unroll
        for (int mi = 0; mi < 4; mi++)
            af[mi] = *(const bf16x8*)&As[(wm + mi * 16 + l16) * 32 + quad * 8];
#pragma unroll
        for (int ni = 0; ni < 4; ni++)
            bfr[ni] = *(const bf16x8*)&Bs[(wn + ni * 16 + l16) * 32 + quad * 8];
#pragma unroll
        for (int mi = 0; mi < 4; mi++)
#pragma unroll
            for (int ni = 0; ni < 4; ni++)
                acc[mi][ni] = MFMA16(af[mi], bfr[ni], acc[mi][ni]);
    }

    if (MODE == 0) {
        const int sel = n0 >> 10;  // 0=q, 1=k, 2=v
        const int nl0 = (n0 & 1023) + wn;
        const float* bias = (sel == 0) ? b0 : ((sel == 1) ? b1 : b2);
        const float qscale = (sel == 0) ? SM_SCALE : 1.0f;
        if (sel < 2) {
            bf16* Cp = (bf16*)((sel == 0) ? out0 : out1);
#pragma unroll
            for (int mi = 0; mi < 4; mi++) {
                const int mbase = m0 + wm + mi * 16 + quad * 4;
#pragma unroll
                for (int ni = 0; ni < 4; ni++) {
                    const int nl = nl0 + ni * 16 + l16;
                    const float bv = bias[nl];
#pragma unroll
                    for (int r = 0; r < 4; r++)
                        Cp[(size_t)(mbase + r) * 1024 + nl] =
                            (bf16)((acc[mi][ni][r] + bv) * qscale);
                }
            }
        } else {
            bf16* Vt = (bf16*)out2;
            const int b = m0 >> 11;  // 2048 rows/batch; 128-row block never straddles
#pragma unroll
            for (int ni = 0; ni < 4; ni++) {
                const int nl = nl0 + ni * 16 + l16;
                const int h = nl >> 6, d = nl & 63;
                const float bv = bias[nl];
                bf16* dst = Vt + ((size_t)(b * 16 + h) * 64 + d) * 2048;
#pragma unroll
                for (int mi = 0; mi < 4; mi++) {
                    const int t0 = (m0 + wm + mi * 16 + quad * 4) & 2047;  // batch-local t
                    bf16x4 w = {(bf16)(acc[mi][ni][0] + bv), (bf16)(acc[mi][ni][1] + bv),
                                (bf16)(acc[mi][ni][2] + bv), (bf16)(acc[mi][ni][3] + bv)};
                    *(bf16x4*)&dst[t0] = w;
                }
            }
        }
    } else {
        float* Cp = (float*)out0;
#pragma unroll
        for (int mi = 0; mi < 4; mi++) {
            const int mbase = m0 + wm + mi * 16 + quad * 4;
#pragma unroll
            for (int ni = 0; ni < 4; ni++) {
                const int n = n0 + wn + ni * 16 + l16;
                const float bv = b0[n];
#pragma unroll
                for (int r = 0; r < 4; r++)
                    Cp[(size_t)(mbase + r) * 1024 + n] = acc[mi][ni][r] + bv;
            }
        }
    }
}

// ---------------- flash attention, causal, hs=64 ----------------
// Unpaired 128-q blocks (grid 16x64, longest-first; queue absorbs imbalance at
// 3 blocks/CU). Double-buffered KV staging (rolling pointers), ONE barrier per
// tile, Q in regs, static softmax (scale pre-folded into q). Strips SHARE one
// per-wave P region serially (pf pulled to regs between) -> LDS 46080 B =
// 3 blocks/CU. l computed by ones-MFMA row-sum (no VALU adds, no shfls).
__device__ __forceinline__ void softmax_static(f32x4* st, bf16* pwrow, int qrel,
                                               bool needmask) {
#pragma unroll
    for (int j = 0; j < 4; j++) {
        bf16x4 w;
#pragma unroll
        for (int r = 0; r < 4; r++) {
            float s = st[j][r];
            if (needmask && (j * 16 + r > qrel)) s = -1e30f;
            w[r] = (bf16)exp2f(s);
        }
        *(bf16x4*)&pwrow[j * 16] = w;  // P[q=l16][kv], r-contiguous b64 write
    }
}

__global__ __launch_bounds__(256) void attn(const bf16* __restrict__ Q,
                                            const bf16* __restrict__ Kg,
                                            const bf16* __restrict__ Vt,
                                            bf16* __restrict__ O) {
    const int bh = blockIdx.y, b = bh >> 4, h = bh & 15;
    const int qblk = 15 - (int)blockIdx.x;  // longest blocks first
    const int q0 = qblk * 128;
    const int tid = threadIdx.x;
    const int wave = tid >> 6, lane = tid & 63;
    const int quad = lane >> 4, l16 = lane & 15;

    __shared__ alignas(16) bf16 KVs[2 * 128 * 72];  // dbuf; per buf: rows 0-63 K, 64-127 V^T
    __shared__ alignas(16) bf16 Ps[4 * 16 * 72];    // one 16x72 P region per wave (shared by strips)

    const bf16* Kbase = Kg + ((size_t)b * 2048) * 1024 + h * 64;
    const bf16* Vbase = Vt + (size_t)bh * 64 * 2048;
    const bf16* Qbase = Q + ((size_t)(b * 2048 + q0)) * 1024 + h * 64;

    bf16* pw = &Ps[(wave * 16 + l16) * 72 + quad * 4];
    const bf16* pr = &Ps[(wave * 16 + l16) * 72 + quad * 8];

    // Q fragments in registers (pre-scaled by SM_SCALE at the QKV GEMM)
    bf16x8 qf[2][2];
#pragma unroll
    for (int s = 0; s < 2; s++)
#pragma unroll
        for (int ks = 0; ks < 2; ks++)
            qf[s][ks] = *(const bf16x8*)&Qbase[(size_t)(wave * 32 + s * 16 + l16) * 1024 +
                                               ks * 32 + quad * 8];

    bf16x8 ones;
#pragma unroll
    for (int j = 0; j < 8; j++) ones[j] = (bf16)1.0f;

    f32x4 ot[2][4] = {};
    f32x4 lacc[2] = {};
    const int qs0 = q0 + wave * 32, qs1 = qs0 + 16;
    const int qg0 = qs0 + l16, qg1 = qs1 + l16;
    const int ntiles = 2 * qblk + 2;
    const int ra = tid >> 3, oa = (tid & 7) * 8;

    // rolling staging pointers (advance by one 64-kv tile per iteration)
    const bf16* pK0 = Kbase + (size_t)ra * 1024 + oa;
    const bf16* pK1 = Kbase + (size_t)(ra + 32) * 1024 + oa;
    const bf16* pV0 = Vbase + (size_t)ra * 2048 + oa;
    const bf16* pV1 = Vbase + (size_t)(ra + 32) * 2048 + oa;

    bf16x8 rc0 = *(const bf16x8*)pK0, rc1 = *(const bf16x8*)pK1;
    bf16x8 rc2 = *(const bf16x8*)pV0, rc3 = *(const bf16x8*)pV1;
    bf16x8 rn0, rn1, rn2, rn3;

#pragma unroll 1
    for (int tk = 0; tk < ntiles; tk++) {
        if (tk + 1 < ntiles) {  // prefetch next tile (flies across barrier+compute)
            rn0 = *(const bf16x8*)(pK0 + 64 * 1024);
            rn1 = *(const bf16x8*)(pK1 + 64 * 1024);
            rn2 = *(const bf16x8*)(pV0 + 64);
            rn3 = *(const bf16x8*)(pV1 + 64);
            pK0 += 64 * 1024; pK1 += 64 * 1024; pV0 += 64; pV1 += 64;
        }
        bf16* buf = &KVs[(tk & 1) * (128 * 72)];
        *(bf16x8*)&buf[ra * 72 + oa] = rc0;
        *(bf16x8*)&buf[(ra + 32) * 72 + oa] = rc1;
        *(bf16x8*)&buf[(64 + ra) * 72 + oa] = rc2;
        *(bf16x8*)&buf[(64 + ra + 32) * 72 + oa] = rc3;
        __syncthreads();  // sole barrier: buf writes visible; other buf's readers done

        const int kv0 = tk * 64;
        const bool act0 = (kv0 <= qs0), act1 = (kv0 <= qs1);
        if (act1) {
            // S^T = K . Q^T for both strips, kf shared in-register
            f32x4 st0[4] = {}, st1[4] = {};
#pragma unroll
            for (int ks = 0; ks < 2; ks++)
#pragma unroll
                for (int j = 0; j < 4; j++) {
                    const bf16x8 kf =
                        *(const bf16x8*)&buf[(j * 16 + l16) * 72 + ks * 32 + quad * 8];
                    if (act0) st0[j] = MFMA16(kf, qf[0][ks], st0[j]);
                    st1[j] = MFMA16(kf, qf[1][ks], st1[j]);
                }

            // strip 0: P write -> pf regs -> l-sum MFMA; then strip 1 reuses the region
            bf16x8 pf0[2], pf1[2];
            if (act0) {
                softmax_static(st0, pw, qg0 - kv0 - quad * 4, kv0 + 63 > qs0);
                pf0[0] = *(const bf16x8*)&pr[0];
                pf0[1] = *(const bf16x8*)&pr[32];
                lacc[0] = MFMA16(ones, pf0[0], lacc[0]);
                lacc[0] = MFMA16(ones, pf0[1], lacc[0]);
            }
            softmax_static(st1, pw, qg1 - kv0 - quad * 4, kv0 + 63 > qs1);
            pf1[0] = *(const bf16x8*)&pr[0];
            pf1[1] = *(const bf16x8*)&pr[32];
            lacc[1] = MFMA16(ones, pf1[0], lacc[1]);
            lacc[1] = MFMA16(ones, pf1[1], lacc[1]);

            // O^T += V^T . P^T
#pragma unroll
            for (int ks = 0; ks < 2; ks++)
#pragma unroll
                for (int db = 0; db < 4; db++) {
                    const bf16x8 vf =
                        *(const bf16x8*)&buf[(64 + db * 16 + l16) * 72 + ks * 32 + quad * 8];
                    if (act0) ot[0][db] = MFMA16(vf, pf0[ks], ot[0][db]);
                    ot[1][db] = MFMA16(vf, pf1[ks], ot[1][db]);
                }
        }
        rc0 = rn0; rc1 = rn1; rc2 = rn2; rc3 = rn3;
    }

    // epilogue: O^T regs -> LDS transpose (reuse KVs) -> coalesced stores
    __syncthreads();
#pragma unroll
    for (int s = 0; s < 2; s++) {
        const float inv = 1.f / lacc[s][0];  // ones-MFMA row-sum: all regs equal
#pragma unroll
        for (int db = 0; db < 4; db++)
#pragma unroll
            for (int r = 0; r < 4; r++)
                KVs[(wave * 32 + s * 16 + l16) * 72 + db * 16 + quad * 4 + r] =
                    (bf16)(ot[s][db][r] * inv);
    }
    __syncthreads();
    const int orow = tid >> 1, oc = (tid & 1) * 32;
    bf16* Obase = O + ((size_t)(b * 2048 + q0 + orow)) * 1024 + h * 64 + oc;
    const bf16* src = &KVs[orow * 72 + oc];
    *(bf16x8*)&Obase[0] = *(const bf16x8*)&src[0];
    *(bf16x8*)&Obase[8] = *(const bf16x8*)&src[8];
    *(bf16x8*)&Obase[16] = *(const bf16x8*)&src[16];
    *(bf16x8*)&Obase[24] = *(const bf16x8*)&src[24];
}

extern "C" void kernel_launch(void* const* d_in, const int* in_sizes, int n_in,
                              void* d_out, int out_size, void* d_ws, size_t ws_size,
                              hipStream_t stream) {
    const float* x = (const float*)d_in[0];
    const float* Wq = (const float*)d_in[1];
    const float* bq = (const float*)d_in[2];
    const float* Wk = (const float*)d_in[3];
    const float* bk = (const float*)d_in[4];
    const float* Wv = (const float*)d_in[5];
    const float* bv = (const float*)d_in[6];
    float* out = (float*)d_out;

    const int M = 8192;  // B*T
    const size_t sz_x = (size_t)M * 1024;
    const size_t sz_w = (size_t)1024 * 1024;

    char* p = (char*)d_ws;
    bf16* xb = (bf16*)p;   p += sz_x * 2;
    bf16* Wcat = (bf16*)p; p += 3 * sz_w * 2;  // [Wq^T ; Wk^T ; Wv^T]
    bf16* qb = (bf16*)p;   p += sz_x * 2;
    bf16* kb = (bf16*)p;   p += sz_x * 2;
    bf16* Vt = (bf16*)p;   p += sz_x * 2;  // [B*H][64][2048]
    bf16* yatt = (bf16*)p; p += sz_x * 2;

    cvt_x<<<dim3(8192), dim3(256), 0, stream>>>(x, xb, (int)sz_x);
    transpose_w3<<<dim3(16, 16, 3), dim3(256), 0, stream>>>(Wq, Wk, Wv, Wcat);

    // fused QKV projection: [8192,1024] @ [1024,3072]
    gemm_bt<0><<<dim3(24, 64), dim3(256), 0, stream>>>(xb, Wcat, bq, bk, bv, qb, kb, Vt,
                                                       M, 3072, 1024);
    attn<<<dim3(16, 64), dim3(256), 0, stream>>>(qb, kb, Vt, yatt);
    // output projection (reference reuses v_proj): yatt @ Wv + bv -> f32 out
    gemm_bt<1><<<dim3(8, 64), dim3(256), 0, stream>>>(yatt, Wcat + 2 * sz_w, bv, bv, bv,
                                                      out, out, out, M, 1024, 1024);
}

// Round 9
// 318.840 us; speedup vs baseline: 1.2733x; 1.2733x over previous
//
#include <hip/hip_runtime.h>
#include <hip/hip_bf16.h>

typedef __bf16 bf16;
typedef __attribute__((ext_vector_type(8))) __bf16 bf16x8;
typedef __attribute__((ext_vector_type(4))) __bf16 bf16x4;
typedef __attribute__((ext_vector_type(4))) float f32x4;

#define MFMA16(a, b, c) __builtin_amdgcn_mfma_f32_16x16x32_bf16((a), (b), (c), 0, 0, 0)
#define SM_SCALE 0.18033688011112043f  // (1/8) * log2(e), folded into q at GEMM epilogue

__device__ __forceinline__ void gld_lds16(const bf16* g, bf16* l) {
    __builtin_amdgcn_global_load_lds((const __attribute__((address_space(1))) void*)g,
                                     (__attribute__((address_space(3))) void*)l, 16, 0, 0);
}

// ---------------- f32 -> bf16 convert (x) ----------------
__global__ __launch_bounds__(256) void cvt_x(const float* __restrict__ in,
                                             bf16* __restrict__ outb, int n) {
    int i = (blockIdx.x * 256 + threadIdx.x) * 4;
    if (i + 3 < n) {
        const float4 v = *(const float4*)(in + i);
        bf16x4 o = {(bf16)v.x, (bf16)v.y, (bf16)v.z, (bf16)v.w};
        *(bf16x4*)(outb + i) = o;
    }
}

// ---------------- W [K][N] f32 -> Wt [N][K] bf16, 3 weights in one launch ----------------
__global__ __launch_bounds__(256) void transpose_w3(const float* __restrict__ W0,
                                                    const float* __restrict__ W1,
                                                    const float* __restrict__ W2,
                                                    bf16* __restrict__ Wt) {
    const float* W = (blockIdx.z == 0) ? W0 : ((blockIdx.z == 1) ? W1 : W2);
    bf16* dst = Wt + (size_t)blockIdx.z * 1024 * 1024;
    __shared__ float tile[64][65];
    const int r0 = blockIdx.y * 64;  // k
    const int c0 = blockIdx.x * 64;  // n
    const int tid = threadIdx.x;
    for (int i = tid; i < 4096; i += 256) {
        int r = i >> 6, cc = i & 63;
        tile[r][cc] = W[(size_t)(r0 + r) * 1024 + c0 + cc];
    }
    __syncthreads();
    for (int i = tid; i < 4096; i += 256) {
        int n = i >> 6, k = i & 63;
        dst[(size_t)(c0 + n) * 1024 + r0 + k] = (bf16)tile[k][n];
    }
}

// ---------------- GEMM: C = A[M,K] @ Bt[N,K]^T + bias ----------------
// MODE 0: fused QKV (N=3072): q output pre-scaled by SM_SCALE; v written
//         transposed into Vt[bh][d][t].   MODE 1: f32 output, N=1024.
template <int MODE>
__global__ __launch_bounds__(256) void gemm_bt(const bf16* __restrict__ A,
                                               const bf16* __restrict__ Bt,
                                               const float* __restrict__ b0,
                                               const float* __restrict__ b1,
                                               const float* __restrict__ b2,
                                               void* __restrict__ out0,
                                               void* __restrict__ out1,
                                               void* __restrict__ out2,
                                               int M, int N, int K) {
    __shared__ alignas(16) bf16 As[128 * 32];
    __shared__ alignas(16) bf16 Bs[128 * 32];
    const int tid = threadIdx.x;
    const int wave = tid >> 6, lane = tid & 63;
    const int quad = lane >> 4, l16 = lane & 15;
    const int m0 = blockIdx.y * 128, n0 = blockIdx.x * 128;
    const int wm = (wave & 1) * 64, wn = (wave >> 1) * 64;

    f32x4 acc[4][4] = {};

    const int srow = lane >> 2, scol = (lane & 3) * 8;
    const bf16* ga = A + (size_t)(m0 + wave * 32 + srow) * K + scol;
    const bf16* gb = Bt + (size_t)(n0 + wave * 32 + srow) * K + scol;
    bf16* la = &As[(wave * 32) * 32];
    bf16* lb = &Bs[(wave * 32) * 32];

    for (int k0 = 0; k0 < K; k0 += 32) {
        __syncthreads();
        gld_lds16(ga + k0, la);
        gld_lds16(ga + k0 + (size_t)16 * K, la + 16 * 32);
        gld_lds16(gb + k0, lb);
        gld_lds16(gb + k0 + (size_t)16 * K, lb + 16 * 32);
        __syncthreads();
        bf16x8 af[4], bfr[4];
#pragma unroll
        for (int mi = 0; mi < 4; mi++)
            af[mi] = *(const bf16x8*)&As[(wm + mi * 16 + l16) * 32 + quad * 8];
#pragma unroll
        for (int ni = 0; ni < 4; ni++)
            bfr[ni] = *(const bf16x8*)&Bs[(wn + ni * 16 + l16) * 32 + quad * 8];
#pragma unroll
        for (int mi = 0; mi < 4; mi++)
#pragma unroll
            for (int ni = 0; ni < 4; ni++)
                acc[mi][ni] = MFMA16(af[mi], bfr[ni], acc[mi][ni]);
    }

    if (MODE == 0) {
        const int sel = n0 >> 10;  // 0=q, 1=k, 2=v
        const int nl0 = (n0 & 1023) + wn;
        const float* bias = (sel == 0) ? b0 : ((sel == 1) ? b1 : b2);
        const float qscale = (sel == 0) ? SM_SCALE : 1.0f;
        if (sel < 2) {
            bf16* Cp = (bf16*)((sel == 0) ? out0 : out1);
#pragma unroll
            for (int mi = 0; mi < 4; mi++) {
                const int mbase = m0 + wm + mi * 16 + quad * 4;
#pragma unroll
                for (int ni = 0; ni < 4; ni++) {
                    const int nl = nl0 + ni * 16 + l16;
                    const float bv = bias[nl];
#pragma unroll
                    for (int r = 0; r < 4; r++)
                        Cp[(size_t)(mbase + r) * 1024 + nl] =
                            (bf16)((acc[mi][ni][r] + bv) * qscale);
                }
            }
        } else {
            bf16* Vt = (bf16*)out2;
            const int b = m0 >> 11;  // 2048 rows/batch; 128-row block never straddles
#pragma unroll
            for (int ni = 0; ni < 4; ni++) {
                const int nl = nl0 + ni * 16 + l16;
                const int h = nl >> 6, d = nl & 63;
                const float bv = bias[nl];
                bf16* dst = Vt + ((size_t)(b * 16 + h) * 64 + d) * 2048;
#pragma unroll
                for (int mi = 0; mi < 4; mi++) {
                    const int t0 = (m0 + wm + mi * 16 + quad * 4) & 2047;  // batch-local t
                    bf16x4 w = {(bf16)(acc[mi][ni][0] + bv), (bf16)(acc[mi][ni][1] + bv),
                                (bf16)(acc[mi][ni][2] + bv), (bf16)(acc[mi][ni][3] + bv)};
                    *(bf16x4*)&dst[t0] = w;
                }
            }
        }
    } else {
        float* Cp = (float*)out0;
#pragma unroll
        for (int mi = 0; mi < 4; mi++) {
            const int mbase = m0 + wm + mi * 16 + quad * 4;
#pragma unroll
            for (int ni = 0; ni < 4; ni++) {
                const int n = n0 + wn + ni * 16 + l16;
                const float bv = b0[n];
#pragma unroll
                for (int r = 0; r < 4; r++)
                    Cp[(size_t)(mbase + r) * 1024 + n] = acc[mi][ni][r] + bv;
            }
        }
    }
}

// ---------------- flash attention, causal, hs=64 ----------------
// 64-q causal pairing: block j does q-strips (31-j) then j -> every block
// exactly 33 KV-tiles (uniform), 1024 blocks, LDS 46080 B -> 3 blocks/CU
// plus a 256-block backfill queue. Each wave owns ONE 16-row q strip: no
// act divergence (all waves active every tile; mask only on diagonal tile).
// Per-tile machinery = R7 proven: dbuf KV staging w/ register prefetch, ONE
// barrier/tile, static softmax (scale in q), per-wave P region (stride 72,
// conflict-free), per-lane l partials + end shfl.
__device__ __forceinline__ void softmax_static(f32x4* st, float& l_i, bf16* pwrow,
                                               int qrel, bool needmask) {
#pragma unroll
    for (int j = 0; j < 4; j++) {
        bf16x4 w;
#pragma unroll
        for (int r = 0; r < 4; r++) {
            float s = st[j][r];
            if (needmask && (j * 16 + r > qrel)) s = -1e30f;
            const float p = exp2f(s);
            l_i += p;
            w[r] = (bf16)p;
        }
        *(bf16x4*)&pwrow[j * 16] = w;  // P[q=l16][kv], r-contiguous b64 write
    }
}

__global__ __launch_bounds__(256) void attn(const bf16* __restrict__ Q,
                                            const bf16* __restrict__ Kg,
                                            const bf16* __restrict__ Vt,
                                            bf16* __restrict__ O) {
    const int bh = blockIdx.y, b = bh >> 4, h = bh & 15;
    const int tid = threadIdx.x;
    const int wave = tid >> 6, lane = tid & 63;
    const int quad = lane >> 4, l16 = lane & 15;

    __shared__ alignas(16) bf16 KVs[2 * 128 * 72];  // dbuf; per buf: rows 0-63 K, 64-127 V^T
    __shared__ alignas(16) bf16 Ps[4 * 16 * 72];    // one 16x72 region per wave

    const bf16* Kbase = Kg + ((size_t)b * 2048) * 1024 + h * 64;
    const bf16* Vbase = Vt + (size_t)bh * 64 * 2048;

    bf16* pw = &Ps[(wave * 16 + l16) * 72 + quad * 4];
    const bf16* pr = &Ps[(wave * 16 + l16) * 72 + quad * 8];
    bf16* ep = &Ps[wave * 16 * 72];  // epilogue region (own wave)

    const int ra = tid >> 3, oa = (tid & 7) * 8;

#pragma unroll 1
    for (int phase = 0; phase < 2; phase++) {
        // causal pairing at 64-q granularity: strip (31-j) then j -> 33 tiles total
        const int qs = (phase == 0) ? (31 - (int)blockIdx.x) : (int)blockIdx.x;
        const int q0 = qs * 64;
        const bf16* Qbase = Q + ((size_t)(b * 2048 + q0)) * 1024 + h * 64;

        // Q fragments in registers (pre-scaled by SM_SCALE at the QKV GEMM)
        bf16x8 qf[2];
#pragma unroll
        for (int ks = 0; ks < 2; ks++)
            qf[ks] = *(const bf16x8*)&Qbase[(size_t)(wave * 16 + l16) * 1024 + ks * 32 + quad * 8];

        float l_i = 0.f;
        f32x4 ot[4] = {};
        const int ntiles = qs + 1;
        const int qrel = wave * 16 + l16 - quad * 4;  // for diagonal-tile mask

        // rolling staging pointers (advance one 64-kv tile per iteration)
        const bf16* pK0 = Kbase + (size_t)ra * 1024 + oa;
        const bf16* pK1 = Kbase + (size_t)(ra + 32) * 1024 + oa;
        const bf16* pV0 = Vbase + (size_t)ra * 2048 + oa;
        const bf16* pV1 = Vbase + (size_t)(ra + 32) * 2048 + oa;

        bf16x8 rc0 = *(const bf16x8*)pK0, rc1 = *(const bf16x8*)pK1;
        bf16x8 rc2 = *(const bf16x8*)pV0, rc3 = *(const bf16x8*)pV1;
        bf16x8 rn0, rn1, rn2, rn3;

#pragma unroll 1
        for (int tk = 0; tk < ntiles; tk++) {
            if (tk + 1 < ntiles) {  // prefetch next tile (flies across barrier+compute)
                rn0 = *(const bf16x8*)(pK0 + 64 * 1024);
                rn1 = *(const bf16x8*)(pK1 + 64 * 1024);
                rn2 = *(const bf16x8*)(pV0 + 64);
                rn3 = *(const bf16x8*)(pV1 + 64);
                pK0 += 64 * 1024; pK1 += 64 * 1024; pV0 += 64; pV1 += 64;
            }
            bf16* buf = &KVs[(tk & 1) * (128 * 72)];
            *(bf16x8*)&buf[ra * 72 + oa] = rc0;
            *(bf16x8*)&buf[(ra + 32) * 72 + oa] = rc1;
            *(bf16x8*)&buf[(64 + ra) * 72 + oa] = rc2;
            *(bf16x8*)&buf[(64 + ra + 32) * 72 + oa] = rc3;
            __syncthreads();  // sole barrier: buf writes visible; other buf's readers done

            // S^T = K . Q^T (every wave active every tile of its phase)
            f32x4 st[4] = {};
#pragma unroll
            for (int ks = 0; ks < 2; ks++)
#pragma unroll
                for (int j = 0; j < 4; j++) {
                    const bf16x8 kf =
                        *(const bf16x8*)&buf[(j * 16 + l16) * 72 + ks * 32 + quad * 8];
                    st[j] = MFMA16(kf, qf[ks], st[j]);
                }

            softmax_static(st, l_i, pw, qrel, tk == ntiles - 1);

            // O^T += V^T . P^T (own-wave Ps readback, no barrier)
#pragma unroll
            for (int ks = 0; ks < 2; ks++) {
                const bf16x8 pf = *(const bf16x8*)&pr[ks * 32];
#pragma unroll
                for (int db = 0; db < 4; db++) {
                    const bf16x8 vf =
                        *(const bf16x8*)&buf[(64 + db * 16 + l16) * 72 + ks * 32 + quad * 8];
                    ot[db] = MFMA16(vf, pf, ot[db]);
                }
            }
            rc0 = rn0; rc1 = rn1; rc2 = rn2; rc3 = rn3;
        }

        // l reduction across the 4 quads (kv was distributed over quads)
        l_i += __shfl_xor(l_i, 16, 64);
        l_i += __shfl_xor(l_i, 32, 64);

        // epilogue: O^T regs -> own-wave Ps transpose -> coalesced stores (no barrier)
        const float inv = 1.f / l_i;
#pragma unroll
        for (int db = 0; db < 4; db++) {
            bf16x4 w = {(bf16)(ot[db][0] * inv), (bf16)(ot[db][1] * inv),
                        (bf16)(ot[db][2] * inv), (bf16)(ot[db][3] * inv)};
            *(bf16x4*)&ep[l16 * 72 + db * 16 + quad * 4] = w;
        }
        {
            const int orow = lane >> 2, oc = (lane & 3) * 16;  // 16 rows x 64 cols per wave
            bf16* Obase =
                O + ((size_t)(b * 2048 + q0 + wave * 16 + orow)) * 1024 + h * 64 + oc;
            const bf16* src = &ep[orow * 72 + oc];
            *(bf16x8*)&Obase[0] = *(const bf16x8*)&src[0];
            *(bf16x8*)&Obase[8] = *(const bf16x8*)&src[8];
        }
        __syncthreads();  // all KVs reads done before next phase's first staging write
    }
}

extern "C" void kernel_launch(void* const* d_in, const int* in_sizes, int n_in,
                              void* d_out, int out_size, void* d_ws, size_t ws_size,
                              hipStream_t stream) {
    const float* x = (const float*)d_in[0];
    const float* Wq = (const float*)d_in[1];
    const float* bq = (const float*)d_in[2];
    const float* Wk = (const float*)d_in[3];
    const float* bk = (const float*)d_in[4];
    const float* Wv = (const float*)d_in[5];
    const float* bv = (const float*)d_in[6];
    float* out = (float*)d_out;

    const int M = 8192;  // B*T
    const size_t sz_x = (size_t)M * 1024;
    const size_t sz_w = (size_t)1024 * 1024;

    char* p = (char*)d_ws;
    bf16* xb = (bf16*)p;   p += sz_x * 2;
    bf16* Wcat = (bf16*)p; p += 3 * sz_w * 2;  // [Wq^T ; Wk^T ; Wv^T]
    bf16* qb = (bf16*)p;   p += sz_x * 2;
    bf16* kb = (bf16*)p;   p += sz_x * 2;
    bf16* Vt = (bf16*)p;   p += sz_x * 2;  // [B*H][64][2048]
    bf16* yatt = (bf16*)p; p += sz_x * 2;

    cvt_x<<<dim3(8192), dim3(256), 0, stream>>>(x, xb, (int)sz_x);
    transpose_w3<<<dim3(16, 16, 3), dim3(256), 0, stream>>>(Wq, Wk, Wv, Wcat);

    // fused QKV projection: [8192,1024] @ [1024,3072]
    gemm_bt<0><<<dim3(24, 64), dim3(256), 0, stream>>>(xb, Wcat, bq, bk, bv, qb, kb, Vt,
                                                       M, 3072, 1024);
    attn<<<dim3(16, 64), dim3(256), 0, stream>>>(qb, kb, Vt, yatt);
    // output projection (reference reuses v_proj): yatt @ Wv + bv -> f32 out
    gemm_bt<1><<<dim3(8, 64), dim3(256), 0, stream>>>(yatt, Wcat + 2 * sz_w, bv, bv, bv,
                                                      out, out, out, M, 1024, 1024);
}